// Round 6
// baseline (2254.785 us; speedup 1.0000x reference)
//
#include <hip/hip_runtime.h>
#include <cstdint>

#define S_LEN 32768
#define NV 256
#define NH 512
#define NR 256

typedef short bf16x8 __attribute__((ext_vector_type(8)));
typedef float f32x4 __attribute__((ext_vector_type(4)));
typedef unsigned short ushort_t;
typedef ushort_t u16x8 __attribute__((ext_vector_type(8)));

// ---------------- bf16 helpers (bit-level, RTNE) ----------------
__device__ __forceinline__ float b2f(ushort_t u) {
  return __uint_as_float(((uint32_t)u) << 16);
}
__device__ __forceinline__ ushort_t f2b(float f) {
  uint32_t x = __float_as_uint(f);
  uint32_t r = (x + 0x7fffu + ((x >> 16) & 1u)) >> 16;
  return (ushort_t)r;
}

// ---------------- host threefry2x32 (key-chain derivation) ----------------
#define TFR(x0,x1,r) { x0 += x1; x1 = ((x1 << (r)) | (x1 >> (32 - (r)))); x1 ^= x0; }
__host__ __forceinline__ void tf2x32(uint32_t k0, uint32_t k1,
                                     uint32_t x0, uint32_t x1,
                                     uint32_t* o0, uint32_t* o1) {
  uint32_t k2 = k0 ^ k1 ^ 0x1BD11BDAu;
  x0 += k0; x1 += k1;
  TFR(x0,x1,13) TFR(x0,x1,15) TFR(x0,x1,26) TFR(x0,x1,6)
  x0 += k1; x1 += k2 + 1u;
  TFR(x0,x1,17) TFR(x0,x1,29) TFR(x0,x1,16) TFR(x0,x1,24)
  x0 += k2; x1 += k0 + 2u;
  TFR(x0,x1,13) TFR(x0,x1,15) TFR(x0,x1,26) TFR(x0,x1,6)
  x0 += k0; x1 += k1 + 3u;
  TFR(x0,x1,17) TFR(x0,x1,29) TFR(x0,x1,16) TFR(x0,x1,24)
  x0 += k1; x1 += k2 + 4u;
  TFR(x0,x1,13) TFR(x0,x1,15) TFR(x0,x1,26) TFR(x0,x1,6)
  x0 += k2; x1 += k0 + 5u;
  *o0 = x0; *o1 = x1;
}

// 20 key pairs passed by value (kernarg segment -> scalar loads)
struct KeyTab { uint32_t a[20]; uint32_t b[20]; };

// ---------------- device RNG: murmur3 full-avalanche counter hash (~11 VALU) --------
__device__ __forceinline__ float fast_uniform(uint32_t k0, uint32_t k1, uint32_t idx) {
  uint32_t h = idx ^ k0;
  h *= 0xCC9E2D51u; h = (h << 15) | (h >> 17); h *= 0x1B873593u;
  h ^= k1;
  h ^= h >> 16; h *= 0x85EBCA6Bu;
  h ^= h >> 13; h *= 0xC2B2AE35u;
  h ^= h >> 16;
  return __uint_as_float((h >> 9) | 0x3f800000u) - 1.0f;
}

__device__ __forceinline__ float wave_reduce(float v) {
#pragma unroll
  for (int o = 32; o > 0; o >>= 1) v += __shfl_down(v, o, 64);
  return v;
}
__device__ __forceinline__ float softplusf(float z) {
  return fmaxf(z, 0.f) + log1pf(expf(-fabsf(z)));
}

#define MFMA16(a, b, c) __builtin_amdgcn_mfma_f32_16x16x32_bf16((a), (b), (c), 0, 0, 0)

// ---------------- plain bf16 MFMA GEMM (round-4 v1 epilogue — measured best) --------
// C[M,N] = A[M,K] @ BT[N,K]^T + biasv.  128x128 tile, BK=64, 4 waves (2x2).
// OUTF32: write f32, else bf16. Scalar epilogue IO (v2 LDS-transpose REGRESSED
// in round 5: +30% on latency-bound kernels from 8 barrier phases + reg pressure).
template<bool OUTF32>
__global__ __launch_bounds__(256)
void gemm_bias(const ushort_t* __restrict__ A, const ushort_t* __restrict__ BT,
               const float* __restrict__ biasv, ushort_t* __restrict__ Cb,
               float* __restrict__ Cf, int M, int N, int K) {
  __shared__ ushort_t Als[128 * 64];
  __shared__ ushort_t Bls[128 * 64];
  const int tid = threadIdx.x;
  const int lane = tid & 63, wave = tid >> 6;
  const int wm = wave >> 1, wn = wave & 1;
  const int q = lane >> 4, l16 = lane & 15;
  const int m0 = blockIdx.y * 128, n0 = blockIdx.x * 128;

  f32x4 acc[4][4];
#pragma unroll
  for (int i = 0; i < 4; i++)
#pragma unroll
    for (int j = 0; j < 4; j++) acc[i][j] = (f32x4){0.f, 0.f, 0.f, 0.f};

  for (int kk = 0; kk < K; kk += 64) {
#pragma unroll
    for (int j = 0; j < 4; j++) {
      int c = j * 256 + tid;
      int r = c >> 3, bl = c & 7, bg = bl ^ (r & 7);
      *(uint4*)&Als[r * 64 + bl * 8] =
          *(const uint4*)&A[(size_t)(m0 + r) * K + kk + bg * 8];
      *(uint4*)&Bls[r * 64 + bl * 8] =
          *(const uint4*)&BT[(size_t)(n0 + r) * K + kk + bg * 8];
    }
    __syncthreads();
#pragma unroll
    for (int c = 0; c < 2; c++) {
      bf16x8 af[4], bf[4];
#pragma unroll
      for (int mt = 0; mt < 4; mt++) {
        int r = wm * 64 + mt * 16 + l16;
        af[mt] = *(const bf16x8*)&Als[r * 64 + (((c * 4 + q) ^ (r & 7)) * 8)];
      }
#pragma unroll
      for (int nt = 0; nt < 4; nt++) {
        int r = wn * 64 + nt * 16 + l16;
        bf[nt] = *(const bf16x8*)&Bls[r * 64 + (((c * 4 + q) ^ (r & 7)) * 8)];
      }
#pragma unroll
      for (int mt = 0; mt < 4; mt++)
#pragma unroll
        for (int nt = 0; nt < 4; nt++)
          acc[mt][nt] = MFMA16(af[mt], bf[nt], acc[mt][nt]);
    }
    __syncthreads();
  }
  // v1 epilogue: C/D layout col = lane&15, row = quad*4 + reg
#pragma unroll
  for (int mt = 0; mt < 4; mt++)
#pragma unroll
    for (int nt = 0; nt < 4; nt++) {
      const int gn = n0 + wn * 64 + nt * 16 + l16;
      const int gmb = m0 + wm * 64 + mt * 16 + q * 4;
      const float bvv = biasv[gn];
#pragma unroll
      for (int rg = 0; rg < 4; rg++) {
        const size_t idx = (size_t)(gmb + rg) * N + gn;
        float z = acc[mt][nt][rg] + bvv;
        if constexpr (OUTF32) Cf[idx] = z; else Cb[idx] = f2b(z);
      }
    }
}

// ---------------- persistent RBM1 CD-5 chain ----------------
// One block owns 32 rows; the whole Gibbs chain runs in LDS (v: 32x256, h: 32x512).
// Replaces 11 global GEMM round-trips (~1.1 GB HBM) with in-LDS ping-pong.
// A-frag layout (m92): lane l: A[m=l&15][k=(l>>4)*8+j]. C-frag: col=l&15,row=q*4+rg.
// B-frags read directly from L2-hot weight arrays (each block reads each W row once).
__global__ __launch_bounds__(256)
void rbm1_chain(const ushort_t* __restrict__ vseq, const ushort_t* __restrict__ W1T,
                const ushort_t* __restrict__ W1N, const ushort_t* __restrict__ bias,
                ushort_t* __restrict__ h1out, double* __restrict__ acc, KeyTab kt) {
  __shared__ ushort_t vb[32 * 264];   // ld 264: row 528B, 16B-aligned, bank-spread
  __shared__ ushort_t hb[32 * 520];   // ld 520: row 1040B
  const int tid = threadIdx.x, lane = tid & 63, w = tid >> 6;
  const int q = lane >> 4, l16 = lane & 15;
  const int m0 = blockIdx.x * 32;

  // load vseq rows -> vb
#pragma unroll
  for (int i = 0; i < 4; i++) {
    int c = i * 256 + tid;                  // 1024 chunks of 8
    int r = c >> 5, c8 = (c & 31) * 8;
    *(u16x8*)&vb[r * 264 + c8] = *(const u16x8*)&vseq[(size_t)(m0 + r) * 256 + c8];
  }
  __syncthreads();

  float cost = 0.f, mon = 0.f;
  // -vseq . bvt
  {
    float s = 0.f;
    for (int i = tid; i < 32 * 256; i += 256) {
      int r = i >> 8, c = i & 255;
      s += b2f(vb[r * 264 + c]) * b2f(bias[(size_t)(m0 + r) * 1280 + c]);
    }
    cost -= s;
  }

#pragma unroll 1
  for (int it = 0; it <= 5; it++) {
    // ---- h-GEMM: z = vb @ W1T^T + bh1t  (N=512, K=256); wave cols [w*128,+128) ----
    bf16x8 af[2][8];
#pragma unroll
    for (int mt = 0; mt < 2; mt++)
#pragma unroll
      for (int ks = 0; ks < 8; ks++)
        af[mt][ks] = *(const bf16x8*)&vb[(mt * 16 + l16) * 264 + ks * 32 + q * 8];
#pragma unroll 1
    for (int nt = 0; nt < 8; nt++) {
      const int n = w * 128 + nt * 16;
      f32x4 ac0 = {0.f, 0.f, 0.f, 0.f}, ac1 = {0.f, 0.f, 0.f, 0.f};
#pragma unroll
      for (int ks = 0; ks < 8; ks++) {
        bf16x8 bf = *(const bf16x8*)&W1T[(size_t)(n + l16) * 256 + ks * 32 + q * 8];
        ac0 = MFMA16(af[0][ks], bf, ac0);
        ac1 = MFMA16(af[1][ks], bf, ac1);
      }
#pragma unroll
      for (int mt = 0; mt < 2; mt++)
#pragma unroll
        for (int rg = 0; rg < 4; rg++) {
          const int row = mt * 16 + q * 4 + rg, col = n + l16, gr = m0 + row;
          float z = (mt ? ac1[rg] : ac0[rg]) + b2f(bias[(size_t)gr * 1280 + 256 + col]);
          if (it == 0) {
            cost -= softplusf(z);
            h1out[(size_t)gr * 512 + col] = f2b(1.f / (1.f + __expf(-z)));
          }
          if (it == 5) {
            cost += softplusf(z);
          } else {
            float e = __expf(-z);
            float u = fast_uniform(kt.a[2 * it], kt.b[2 * it],
                                   (uint32_t)(gr * 512 + col));
            hb[row * 520 + col] = (fmaf(u, e, u) < 1.f) ? (ushort_t)0x3f80
                                                        : (ushort_t)0;
          }
        }
    }
    if (it == 5) break;
    __syncthreads();  // hb writes visible

    // ---- v-GEMM: z = hb @ W1N^T + bvt  (N=256, K=512); wave cols [w*64,+64) ----
    f32x4 av[4][2];
#pragma unroll
    for (int nt = 0; nt < 4; nt++)
#pragma unroll
      for (int mt = 0; mt < 2; mt++) av[nt][mt] = (f32x4){0.f, 0.f, 0.f, 0.f};
#pragma unroll 1
    for (int hf = 0; hf < 2; hf++) {
      bf16x8 a2[2][8];
#pragma unroll
      for (int mt = 0; mt < 2; mt++)
#pragma unroll
        for (int ks = 0; ks < 8; ks++)
          a2[mt][ks] = *(const bf16x8*)&hb[(mt * 16 + l16) * 520 + hf * 256 +
                                           ks * 32 + q * 8];
#pragma unroll 1
      for (int nt = 0; nt < 4; nt++) {
        const int n = w * 64 + nt * 16;
#pragma unroll
        for (int ks = 0; ks < 8; ks++) {
          bf16x8 bf = *(const bf16x8*)&W1N[(size_t)(n + l16) * 512 + hf * 256 +
                                           ks * 32 + q * 8];
          av[nt][0] = MFMA16(a2[0][ks], bf, av[nt][0]);
          av[nt][1] = MFMA16(a2[1][ks], bf, av[nt][1]);
        }
      }
    }
#pragma unroll
    for (int nt = 0; nt < 4; nt++)
#pragma unroll
      for (int mt = 0; mt < 2; mt++)
#pragma unroll
        for (int rg = 0; rg < 4; rg++) {
          const int row = mt * 16 + q * 4 + rg, col = w * 64 + nt * 16 + l16;
          const int gr = m0 + row;
          float z = av[nt][mt][rg] + b2f(bias[(size_t)gr * 1280 + col]);
          float e = __expf(-z);
          float u = fast_uniform(kt.a[2 * it + 1], kt.b[2 * it + 1],
                                 (uint32_t)(gr * 256 + col));
          vb[row * 264 + col] = (fmaf(u, e, u) < 1.f) ? (ushort_t)0x3f80
                                                      : (ushort_t)0;
          if (it == 4) {  // monitor vs vseq on last mean_v
            float p = __builtin_amdgcn_rcpf(1.f + e);
            ushort_t v = vseq[(size_t)gr * 256 + col];
            mon += v ? logf(p + 1e-10f) : logf(1.f - p + 1e-10f);
          }
        }
    __syncthreads();  // vb writes visible for next h-GEMM
    if (it == 4) {    // +vfin . bvt
      float s = 0.f;
      for (int i = tid; i < 32 * 256; i += 256) {
        int r = i >> 8, c = i & 255;
        s += b2f(vb[r * 264 + c]) * b2f(bias[(size_t)(m0 + r) * 1280 + c]);
      }
      cost += s;
    }
  }
  cost = wave_reduce(cost);
  mon = wave_reduce(mon);
  if (lane == 0) {
    atomicAdd(acc, (double)cost);
    atomicAdd(acc + 1, (double)mon);
  }
}

// ---------------- persistent RBM2 CD-5 chain (512<->512) ----------------
__global__ __launch_bounds__(256)
void rbm2_chain(const ushort_t* __restrict__ h1in, const ushort_t* __restrict__ W2T,
                const ushort_t* __restrict__ W2N, const ushort_t* __restrict__ bias,
                double* __restrict__ acc, KeyTab kt) {
  __shared__ ushort_t ab[32 * 520];   // h1 side
  __shared__ ushort_t bb[32 * 520];   // h2 side
  const int tid = threadIdx.x, lane = tid & 63, w = tid >> 6;
  const int q = lane >> 4, l16 = lane & 15;
  const int m0 = blockIdx.x * 32;

#pragma unroll
  for (int i = 0; i < 8; i++) {
    int c = i * 256 + tid;                  // 2048 chunks of 8
    int r = c >> 6, c8 = (c & 63) * 8;
    *(u16x8*)&ab[r * 520 + c8] = *(const u16x8*)&h1in[(size_t)(m0 + r) * 512 + c8];
  }
  __syncthreads();

  float cost = 0.f;
  {  // -h1 . bh1t
    float s = 0.f;
    for (int i = tid; i < 32 * 512; i += 256) {
      int r = i >> 9, c = i & 511;
      s += b2f(ab[r * 520 + c]) * b2f(bias[(size_t)(m0 + r) * 1280 + 256 + c]);
    }
    cost -= s;
  }

#pragma unroll 1
  for (int it = 0; it <= 5; it++) {
    // ---- h2-GEMM: z = ab @ W2T^T + bh2t (N=512, K=512) ----
    f32x4 ah[8][2];
#pragma unroll
    for (int nt = 0; nt < 8; nt++)
#pragma unroll
      for (int mt = 0; mt < 2; mt++) ah[nt][mt] = (f32x4){0.f, 0.f, 0.f, 0.f};
#pragma unroll 1
    for (int hf = 0; hf < 2; hf++) {
      bf16x8 af[2][8];
#pragma unroll
      for (int mt = 0; mt < 2; mt++)
#pragma unroll
        for (int ks = 0; ks < 8; ks++)
          af[mt][ks] = *(const bf16x8*)&ab[(mt * 16 + l16) * 520 + hf * 256 +
                                           ks * 32 + q * 8];
#pragma unroll 1
      for (int nt = 0; nt < 8; nt++) {
        const int n = w * 128 + nt * 16;
#pragma unroll
        for (int ks = 0; ks < 8; ks++) {
          bf16x8 bf = *(const bf16x8*)&W2T[(size_t)(n + l16) * 512 + hf * 256 +
                                           ks * 32 + q * 8];
          ah[nt][0] = MFMA16(af[0][ks], bf, ah[nt][0]);
          ah[nt][1] = MFMA16(af[1][ks], bf, ah[nt][1]);
        }
      }
    }
#pragma unroll
    for (int nt = 0; nt < 8; nt++)
#pragma unroll
      for (int mt = 0; mt < 2; mt++)
#pragma unroll
        for (int rg = 0; rg < 4; rg++) {
          const int row = mt * 16 + q * 4 + rg, col = w * 128 + nt * 16 + l16;
          const int gr = m0 + row;
          float z = ah[nt][mt][rg] + b2f(bias[(size_t)gr * 1280 + 768 + col]);
          if (it == 0) cost -= softplusf(z);
          if (it == 5) {
            cost += softplusf(z);
          } else {
            float e = __expf(-z);
            float u = fast_uniform(kt.a[10 + 2 * it], kt.b[10 + 2 * it],
                                   (uint32_t)(gr * 512 + col));
            bb[row * 520 + col] = (fmaf(u, e, u) < 1.f) ? (ushort_t)0x3f80
                                                        : (ushort_t)0;
          }
        }
    if (it == 5) break;
    __syncthreads();

    // ---- h1'-GEMM: z = bb @ W2N^T + bh1t (N=512, K=512) ----
    f32x4 av[8][2];
#pragma unroll
    for (int nt = 0; nt < 8; nt++)
#pragma unroll
      for (int mt = 0; mt < 2; mt++) av[nt][mt] = (f32x4){0.f, 0.f, 0.f, 0.f};
#pragma unroll 1
    for (int hf = 0; hf < 2; hf++) {
      bf16x8 af[2][8];
#pragma unroll
      for (int mt = 0; mt < 2; mt++)
#pragma unroll
        for (int ks = 0; ks < 8; ks++)
          af[mt][ks] = *(const bf16x8*)&bb[(mt * 16 + l16) * 520 + hf * 256 +
                                           ks * 32 + q * 8];
#pragma unroll 1
      for (int nt = 0; nt < 8; nt++) {
        const int n = w * 128 + nt * 16;
#pragma unroll
        for (int ks = 0; ks < 8; ks++) {
          bf16x8 bf = *(const bf16x8*)&W2N[(size_t)(n + l16) * 512 + hf * 256 +
                                           ks * 32 + q * 8];
          av[nt][0] = MFMA16(af[0][ks], bf, av[nt][0]);
          av[nt][1] = MFMA16(af[1][ks], bf, av[nt][1]);
        }
      }
    }
#pragma unroll
    for (int nt = 0; nt < 8; nt++)
#pragma unroll
      for (int mt = 0; mt < 2; mt++)
#pragma unroll
        for (int rg = 0; rg < 4; rg++) {
          const int row = mt * 16 + q * 4 + rg, col = w * 128 + nt * 16 + l16;
          const int gr = m0 + row;
          float z = av[nt][mt][rg] + b2f(bias[(size_t)gr * 1280 + 256 + col]);
          float e = __expf(-z);
          float u = fast_uniform(kt.a[11 + 2 * it], kt.b[11 + 2 * it],
                                 (uint32_t)(gr * 512 + col));
          ab[row * 520 + col] = (fmaf(u, e, u) < 1.f) ? (ushort_t)0x3f80
                                                      : (ushort_t)0;
        }
    __syncthreads();
    if (it == 4) {  // +h1fin . bh1t
      float s = 0.f;
      for (int i = tid; i < 32 * 512; i += 256) {
        int r = i >> 9, c = i & 511;
        s += b2f(ab[r * 520 + c]) * b2f(bias[(size_t)(m0 + r) * 1280 + 256 + c]);
      }
      cost += s;
    }
  }
  cost = wave_reduce(cost);
  if (lane == 0) atomicAdd(acc, (double)cost);
}

// ---------------- chunked RNN scan v3 (round-5 proven: conflicts 4.2e7 -> 327k) -----
__global__ __launch_bounds__(512, 2)
void rnn_scan(const float* __restrict__ Apre, const float* __restrict__ Wuu,
              ushort_t* __restrict__ shifted) {
  const int tid = threadIdx.x;
  const int j = tid >> 1;
  const int s = tid & 1;
  const int t_begin = blockIdx.x * 128;
  const int t_end = t_begin + 128;
  const int t0 = (t_begin >= 32) ? (t_begin - 32) : 0;

  float w[128];
#pragma unroll
  for (int i = 0; i < 128; i++) w[i] = Wuu[(size_t)(s * 128 + i) * 256 + j];

  __shared__ float u[2][264];
  __shared__ float asg[16 * 256];
  if (tid < 256) u[0][tid + (tid >> 7) * 4] = 0.f;
  if (blockIdx.x == 0 && s == 0) shifted[j] = 0;
  __syncthreads();

  const int jp = j + (j >> 7) * 4;
  int p = 0;
  for (int tb = t0; tb < t_end; tb += 16) {
    float4 a0 = *(const float4*)&Apre[(size_t)tb * 256 + tid * 8];
    float4 a1 = *(const float4*)&Apre[(size_t)tb * 256 + tid * 8 + 4];
    *(float4*)&asg[tid * 8] = a0;
    *(float4*)&asg[tid * 8 + 4] = a1;
    __syncthreads();
#pragma unroll 1
    for (int i = 0; i < 16; i++) {
      const int t = tb + i;
      float p0 = 0.f, p1 = 0.f, p2 = 0.f, p3 = 0.f;
#pragma unroll
      for (int qq = 0; qq < 128; qq += 4) {
        float4 uv = *(const float4*)&u[p][s * 132 + qq];
        p0 = fmaf(uv.x, w[qq + 0], p0);
        p1 = fmaf(uv.y, w[qq + 1], p1);
        p2 = fmaf(uv.z, w[qq + 2], p2);
        p3 = fmaf(uv.w, w[qq + 3], p3);
      }
      float ps = (p0 + p1) + (p2 + p3);
      ps += __shfl_xor(ps, 1, 64);
      float z = asg[i * 256 + j] + ps;
      float e = __expf(2.f * z);
      float unew = 1.f - 2.f * __builtin_amdgcn_rcpf(e + 1.f);
      if (s == 0) {
        u[1 - p][jp] = unew;
        if (t >= t_begin && (t + 1) < S_LEN)
          shifted[(size_t)(t + 1) * 256 + j] = f2b(unew);
      }
      __syncthreads();
      p ^= 1;
    }
  }
}

// ---------------- prep ----------------
__global__ __launch_bounds__(256)
void conv_b16(const float* __restrict__ src, ushort_t* __restrict__ dst, int n) {
  int i = blockIdx.x * 256 + threadIdx.x;
  if (i < n) dst[i] = f2b(src[i]);
}
__global__ __launch_bounds__(256)
void transp_b16(const float* __restrict__ src, ushort_t* __restrict__ dst, int R, int C) {
  int i = blockIdx.x * 256 + threadIdx.x;
  if (i < R * C) {
    int r = i / C, c = i - r * C;
    dst[(size_t)c * R + r] = f2b(src[i]);
  }
}

__global__ void finalize_kernel(const double* __restrict__ acc, float* __restrict__ out) {
  out[0] = (float)(acc[0] / (double)S_LEN);
  out[1] = (float)(acc[1] / (double)S_LEN);
}

// ---------------- host orchestration ----------------
extern "C" void kernel_launch(void* const* d_in, const int* in_sizes, int n_in,
                              void* d_out, int out_size, void* d_ws, size_t ws_size,
                              hipStream_t stream) {
  (void)in_sizes; (void)n_in; (void)out_size; (void)ws_size;
  const float* v_seq = (const float*)d_in[0];
  const float* W1    = (const float*)d_in[1];
  const float* bv    = (const float*)d_in[2];
  const float* bh1   = (const float*)d_in[3];
  const float* W2    = (const float*)d_in[4];
  const float* bh2   = (const float*)d_in[5];
  const float* Wyv   = (const float*)d_in[6];
  const float* Wyh1  = (const float*)d_in[7];
  const float* Wyh2  = (const float*)d_in[8];
  const float* Wvu   = (const float*)d_in[9];
  const float* Wuu   = (const float*)d_in[10];
  const float* bu    = (const float*)d_in[11];
  float* out = (float*)d_out;

  const size_t SN = (size_t)S_LEN * NV;
  const int NB = NV + NH + NH;  // 1280
  char* base = (char*)d_ws;
  size_t cur = 0;
  auto take = [&](size_t bytes) { size_t o = cur; cur += (bytes + 255) & ~(size_t)255; return o; };
  double*   acc      = (double*)  (base + take(64));
  ushort_t* BTwvu    = (ushort_t*)(base + take(65536 * 2));
  ushort_t* Wycat    = (ushort_t*)(base + take((size_t)NB * NR * 2));
  float*    bveccat  = (float*)   (base + take(NB * 4));
  ushort_t* BTw1     = (ushort_t*)(base + take(131072 * 2));   // W1^T [512,256]
  ushort_t* BTw1t    = (ushort_t*)(base + take(131072 * 2));   // W1   [256,512]
  ushort_t* BTw2     = (ushort_t*)(base + take(262144 * 2));   // W2^T [512,512]
  ushort_t* BTw2t    = (ushort_t*)(base + take(262144 * 2));   // W2   [512,512]
  ushort_t* vseq_bf  = (ushort_t*)(base + take(SN * 2));
  ushort_t* shifted  = (ushort_t*)(base + take(SN * 2));
  ushort_t* bias_cat = (ushort_t*)(base + take((size_t)S_LEN * NB * 2)); // [S,1280]
  ushort_t* h1buf    = (ushort_t*)(base + take((size_t)S_LEN * NH * 2));
  float* Arnn = (float*)bias_cat;  // f32 [S,256] alias; consumed before bias GEMM

  // key chain (host): key(42); 10x (key,k1,k2)=split(key,3)
  KeyTab kt;
  uint32_t K0 = 0u, K1 = 42u;
  for (int it = 0; it < 10; it++) {
    uint32_t n0, n1, a0, a1, b0, b1;
    tf2x32(K0, K1, 0u, 0u, &n0, &n1);
    tf2x32(K0, K1, 0u, 1u, &a0, &a1);
    tf2x32(K0, K1, 0u, 2u, &b0, &b1);
    kt.a[2 * it] = a0; kt.b[2 * it] = a1;
    kt.a[2 * it + 1] = b0; kt.b[2 * it + 1] = b1;
    K0 = n0; K1 = n1;
  }

  hipMemsetAsync(acc, 0, 2 * sizeof(double), stream);

  dim3 blk(256);
  conv_b16<<<dim3((int)((SN + 255) / 256)), blk, 0, stream>>>(v_seq, vseq_bf, (int)SN);
  conv_b16<<<dim3(256), blk, 0, stream>>>(Wyv, Wycat, 65536);
  conv_b16<<<dim3(512), blk, 0, stream>>>(Wyh1, Wycat + 65536, 131072);
  conv_b16<<<dim3(512), blk, 0, stream>>>(Wyh2, Wycat + 196608, 131072);
  conv_b16<<<dim3(512), blk, 0, stream>>>(W1, BTw1t, 131072);
  conv_b16<<<dim3(1024), blk, 0, stream>>>(W2, BTw2t, 262144);
  transp_b16<<<dim3(256), blk, 0, stream>>>(Wvu, BTwvu, 256, 256);
  transp_b16<<<dim3(512), blk, 0, stream>>>(W1, BTw1, 256, 512);
  transp_b16<<<dim3(1024), blk, 0, stream>>>(W2, BTw2, 512, 512);
  hipMemcpyAsync(bveccat,           bv,  NV * 4, hipMemcpyDeviceToDevice, stream);
  hipMemcpyAsync(bveccat + NV,      bh1, NH * 4, hipMemcpyDeviceToDevice, stream);
  hipMemcpyAsync(bveccat + NV + NH, bh2, NH * 4, hipMemcpyDeviceToDevice, stream);

  const int M = S_LEN;
  // 1) Arnn = v_seq @ Wvu + bu (f32)
  gemm_bias<true><<<dim3(NV / 128, M / 128), blk, 0, stream>>>(
      vseq_bf, BTwvu, bu, nullptr, Arnn, M, NV, NV);
  // 2) scan -> shifted
  rnn_scan<<<dim3(S_LEN / 128), dim3(512), 0, stream>>>(Arnn, Wuu, shifted);
  // 3) bias_cat = shifted @ Wycat^T + bveccat (bf16)
  gemm_bias<false><<<dim3(NB / 128, M / 128), blk, 0, stream>>>(
      shifted, Wycat, bveccat, bias_cat, nullptr, M, NB, NR);
  // 4) RBM1 chain (writes h1buf, accumulates cost1 + monitor)
  rbm1_chain<<<dim3(S_LEN / 32), blk, 0, stream>>>(
      vseq_bf, BTw1, BTw1t, bias_cat, h1buf, acc, kt);
  // 5) RBM2 chain (accumulates cost2)
  rbm2_chain<<<dim3(S_LEN / 32), blk, 0, stream>>>(
      h1buf, BTw2, BTw2t, bias_cat, acc, kt);

  finalize_kernel<<<1, 1, 0, stream>>>(acc, out);
}

// Round 7
// 1972.695 us; speedup vs baseline: 1.1430x; 1.1430x over previous
//
#include <hip/hip_runtime.h>
#include <cstdint>

#define S_LEN 32768
#define NV 256
#define NH 512
#define NR 256

typedef short bf16x8 __attribute__((ext_vector_type(8)));
typedef float f32x4 __attribute__((ext_vector_type(4)));
typedef unsigned short ushort_t;
typedef ushort_t u16x8 __attribute__((ext_vector_type(8)));

// ---------------- bf16 helpers (bit-level, RTNE) ----------------
__device__ __forceinline__ float b2f(ushort_t u) {
  return __uint_as_float(((uint32_t)u) << 16);
}
__device__ __forceinline__ ushort_t f2b(float f) {
  uint32_t x = __float_as_uint(f);
  uint32_t r = (x + 0x7fffu + ((x >> 16) & 1u)) >> 16;
  return (ushort_t)r;
}

// nontemporal stream helpers (keep L2 for weights)
__device__ __forceinline__ u16x8 ldnt8(const ushort_t* p) {
  return __builtin_nontemporal_load((const u16x8*)p);
}
__device__ __forceinline__ ushort_t ldnt1(const ushort_t* p) {
  return __builtin_nontemporal_load(p);
}
__device__ __forceinline__ void stnt1(ushort_t* p, ushort_t v) {
  __builtin_nontemporal_store(v, p);
}

// ---------------- host threefry2x32 (key-chain derivation) ----------------
#define TFR(x0,x1,r) { x0 += x1; x1 = ((x1 << (r)) | (x1 >> (32 - (r)))); x1 ^= x0; }
__host__ __forceinline__ void tf2x32(uint32_t k0, uint32_t k1,
                                     uint32_t x0, uint32_t x1,
                                     uint32_t* o0, uint32_t* o1) {
  uint32_t k2 = k0 ^ k1 ^ 0x1BD11BDAu;
  x0 += k0; x1 += k1;
  TFR(x0,x1,13) TFR(x0,x1,15) TFR(x0,x1,26) TFR(x0,x1,6)
  x0 += k1; x1 += k2 + 1u;
  TFR(x0,x1,17) TFR(x0,x1,29) TFR(x0,x1,16) TFR(x0,x1,24)
  x0 += k2; x1 += k0 + 2u;
  TFR(x0,x1,13) TFR(x0,x1,15) TFR(x0,x1,26) TFR(x0,x1,6)
  x0 += k0; x1 += k1 + 3u;
  TFR(x0,x1,17) TFR(x0,x1,29) TFR(x0,x1,16) TFR(x0,x1,24)
  x0 += k1; x1 += k2 + 4u;
  TFR(x0,x1,13) TFR(x0,x1,15) TFR(x0,x1,26) TFR(x0,x1,6)
  x0 += k2; x1 += k0 + 5u;
  *o0 = x0; *o1 = x1;
}

struct KeyTab { uint32_t a[20]; uint32_t b[20]; };

// ---------------- device RNG: murmur3 full-avalanche counter hash (~11 VALU) --------
__device__ __forceinline__ float fast_uniform(uint32_t k0, uint32_t k1, uint32_t idx) {
  uint32_t h = idx ^ k0;
  h *= 0xCC9E2D51u; h = (h << 15) | (h >> 17); h *= 0x1B873593u;
  h ^= k1;
  h ^= h >> 16; h *= 0x85EBCA6Bu;
  h ^= h >> 13; h *= 0xC2B2AE35u;
  h ^= h >> 16;
  return __uint_as_float((h >> 9) | 0x3f800000u) - 1.0f;
}

__device__ __forceinline__ float wave_reduce(float v) {
#pragma unroll
  for (int o = 32; o > 0; o >>= 1) v += __shfl_down(v, o, 64);
  return v;
}
__device__ __forceinline__ float softplusf(float z) {
  return fmaxf(z, 0.f) + log1pf(expf(-fabsf(z)));
}

#define MFMA16(a, b, c) __builtin_amdgcn_mfma_f32_16x16x32_bf16((a), (b), (c), 0, 0, 0)

// ---------------- plain bf16 MFMA GEMM (round-4 v1 epilogue — measured best) --------
template<bool OUTF32>
__global__ __launch_bounds__(256)
void gemm_bias(const ushort_t* __restrict__ A, const ushort_t* __restrict__ BT,
               const float* __restrict__ biasv, ushort_t* __restrict__ Cb,
               float* __restrict__ Cf, int M, int N, int K) {
  __shared__ ushort_t Als[128 * 64];
  __shared__ ushort_t Bls[128 * 64];
  const int tid = threadIdx.x;
  const int lane = tid & 63, wave = tid >> 6;
  const int wm = wave >> 1, wn = wave & 1;
  const int q = lane >> 4, l16 = lane & 15;
  const int m0 = blockIdx.y * 128, n0 = blockIdx.x * 128;

  f32x4 acc[4][4];
#pragma unroll
  for (int i = 0; i < 4; i++)
#pragma unroll
    for (int j = 0; j < 4; j++) acc[i][j] = (f32x4){0.f, 0.f, 0.f, 0.f};

  for (int kk = 0; kk < K; kk += 64) {
#pragma unroll
    for (int j = 0; j < 4; j++) {
      int c = j * 256 + tid;
      int r = c >> 3, bl = c & 7, bg = bl ^ (r & 7);
      *(uint4*)&Als[r * 64 + bl * 8] =
          *(const uint4*)&A[(size_t)(m0 + r) * K + kk + bg * 8];
      *(uint4*)&Bls[r * 64 + bl * 8] =
          *(const uint4*)&BT[(size_t)(n0 + r) * K + kk + bg * 8];
    }
    __syncthreads();
#pragma unroll
    for (int c = 0; c < 2; c++) {
      bf16x8 af[4], bf[4];
#pragma unroll
      for (int mt = 0; mt < 4; mt++) {
        int r = wm * 64 + mt * 16 + l16;
        af[mt] = *(const bf16x8*)&Als[r * 64 + (((c * 4 + q) ^ (r & 7)) * 8)];
      }
#pragma unroll
      for (int nt = 0; nt < 4; nt++) {
        int r = wn * 64 + nt * 16 + l16;
        bf[nt] = *(const bf16x8*)&Bls[r * 64 + (((c * 4 + q) ^ (r & 7)) * 8)];
      }
#pragma unroll
      for (int mt = 0; mt < 4; mt++)
#pragma unroll
        for (int nt = 0; nt < 4; nt++)
          acc[mt][nt] = MFMA16(af[mt], bf[nt], acc[mt][nt]);
    }
    __syncthreads();
  }
#pragma unroll
  for (int mt = 0; mt < 4; mt++)
#pragma unroll
    for (int nt = 0; nt < 4; nt++) {
      const int gn = n0 + wn * 64 + nt * 16 + l16;
      const int gmb = m0 + wm * 64 + mt * 16 + q * 4;
      const float bvv = biasv[gn];
#pragma unroll
      for (int rg = 0; rg < 4; rg++) {
        const size_t idx = (size_t)(gmb + rg) * N + gn;
        float z = acc[mt][nt][rg] + bvv;
        if constexpr (OUTF32) Cf[idx] = z; else Cb[idx] = f2b(z);
      }
    }
}

// ---------------- persistent RBM1 CD-5 chain ----------------
// One block owns 32 rows; the whole Gibbs chain runs in LDS (v: 32x264, h: 32x520).
// ROUND-6 BUG FIX: accumulators were arrays indexed by an unroll(1) induction var
// (nt) -> alloca/scratch -> every MFMA round-tripped HBM-backed scratch (2 GB
// WRITE_SIZE measured). Now: A-frags hoisted into constant-indexed regs, per-nt
// local f32x4 accumulators, epilogue inside the nt body. No dynamic reg indexing.
__global__ __launch_bounds__(256)
void rbm1_chain(const ushort_t* __restrict__ vseq, const ushort_t* __restrict__ W1T,
                const ushort_t* __restrict__ W1N, const ushort_t* __restrict__ bias,
                ushort_t* __restrict__ h1out, double* __restrict__ acc, KeyTab kt) {
  __shared__ ushort_t vb[32 * 264];
  __shared__ ushort_t hb[32 * 520];
  const int tid = threadIdx.x, lane = tid & 63, w = tid >> 6;
  const int q = lane >> 4, l16 = lane & 15;
  const int m0 = blockIdx.x * 32;

#pragma unroll
  for (int i = 0; i < 4; i++) {
    int c = i * 256 + tid;
    int r = c >> 5, c8 = (c & 31) * 8;
    *(u16x8*)&vb[r * 264 + c8] = ldnt8(&vseq[(size_t)(m0 + r) * 256 + c8]);
  }
  __syncthreads();

  float cost = 0.f, mon = 0.f;
  {  // -vseq . bvt
    float s = 0.f;
    for (int i = tid; i < 32 * 256; i += 256) {
      int r = i >> 8, c = i & 255;
      s += b2f(vb[r * 264 + c]) * b2f(bias[(size_t)(m0 + r) * 1280 + c]);
    }
    cost -= s;
  }

#pragma unroll 1
  for (int it = 0; it <= 5; it++) {
    // ---- h-GEMM: z = vb @ W1T^T + bh1t (N=512, K=256); wave cols [w*128,+128) ----
    bf16x8 af[2][8];  // constant-indexed (mt,ks unrolled) -> registers
#pragma unroll
    for (int mt = 0; mt < 2; mt++)
#pragma unroll
      for (int ks = 0; ks < 8; ks++)
        af[mt][ks] = *(const bf16x8*)&vb[(mt * 16 + l16) * 264 + ks * 32 + q * 8];
#pragma unroll 1
    for (int nt = 0; nt < 8; nt++) {
      const int n = w * 128 + nt * 16;
      f32x4 ac0 = {0.f, 0.f, 0.f, 0.f}, ac1 = {0.f, 0.f, 0.f, 0.f};
#pragma unroll
      for (int ks = 0; ks < 8; ks++) {
        bf16x8 bf = *(const bf16x8*)&W1T[(size_t)(n + l16) * 256 + ks * 32 + q * 8];
        ac0 = MFMA16(af[0][ks], bf, ac0);
        ac1 = MFMA16(af[1][ks], bf, ac1);
      }
#pragma unroll
      for (int mt = 0; mt < 2; mt++)
#pragma unroll
        for (int rg = 0; rg < 4; rg++) {
          const int row = mt * 16 + q * 4 + rg, col = n + l16, gr = m0 + row;
          float z = (mt ? ac1[rg] : ac0[rg]) + b2f(bias[(size_t)gr * 1280 + 256 + col]);
          if (it == 0) {
            cost -= softplusf(z);
            stnt1(&h1out[(size_t)gr * 512 + col], f2b(1.f / (1.f + __expf(-z))));
          }
          if (it == 5) {
            cost += softplusf(z);
          } else {
            float e = __expf(-z);
            float u = fast_uniform(kt.a[2 * it], kt.b[2 * it],
                                   (uint32_t)(gr * 512 + col));
            hb[row * 520 + col] = (fmaf(u, e, u) < 1.f) ? (ushort_t)0x3f80
                                                        : (ushort_t)0;
          }
        }
    }
    if (it == 5) break;
    __syncthreads();  // hb visible

    // ---- v-GEMM: z = hb @ W1N^T + bvt (N=256, K=512); wave cols [w*64,+64) ----
    bf16x8 a2[2][2][8];  // [hf][mt][ks], all constant-indexed -> 128 VGPRs
#pragma unroll
    for (int hf = 0; hf < 2; hf++)
#pragma unroll
      for (int mt = 0; mt < 2; mt++)
#pragma unroll
        for (int ks = 0; ks < 8; ks++)
          a2[hf][mt][ks] = *(const bf16x8*)&hb[(mt * 16 + l16) * 520 + hf * 256 +
                                               ks * 32 + q * 8];
#pragma unroll 1
    for (int nt = 0; nt < 4; nt++) {
      const int n = w * 64 + nt * 16;
      f32x4 ac0 = {0.f, 0.f, 0.f, 0.f}, ac1 = {0.f, 0.f, 0.f, 0.f};
#pragma unroll
      for (int hf = 0; hf < 2; hf++)
#pragma unroll
        for (int ks = 0; ks < 8; ks++) {
          bf16x8 bf = *(const bf16x8*)&W1N[(size_t)(n + l16) * 512 + hf * 256 +
                                           ks * 32 + q * 8];
          ac0 = MFMA16(a2[hf][0][ks], bf, ac0);
          ac1 = MFMA16(a2[hf][1][ks], bf, ac1);
        }
#pragma unroll
      for (int mt = 0; mt < 2; mt++)
#pragma unroll
        for (int rg = 0; rg < 4; rg++) {
          const int row = mt * 16 + q * 4 + rg, col = n + l16, gr = m0 + row;
          float z = (mt ? ac1[rg] : ac0[rg]) + b2f(bias[(size_t)gr * 1280 + col]);
          float e = __expf(-z);
          float u = fast_uniform(kt.a[2 * it + 1], kt.b[2 * it + 1],
                                 (uint32_t)(gr * 256 + col));
          vb[row * 264 + col] = (fmaf(u, e, u) < 1.f) ? (ushort_t)0x3f80
                                                      : (ushort_t)0;
          if (it == 4) {  // monitor vs vseq on last mean_v
            float p = __builtin_amdgcn_rcpf(1.f + e);
            ushort_t v = ldnt1(&vseq[(size_t)gr * 256 + col]);
            mon += v ? logf(p + 1e-10f) : logf(1.f - p + 1e-10f);
          }
        }
    }
    __syncthreads();  // vb visible
    if (it == 4) {    // +vfin . bvt
      float s = 0.f;
      for (int i = tid; i < 32 * 256; i += 256) {
        int r = i >> 8, c = i & 255;
        s += b2f(vb[r * 264 + c]) * b2f(bias[(size_t)(m0 + r) * 1280 + c]);
      }
      cost += s;
    }
  }
  cost = wave_reduce(cost);
  mon = wave_reduce(mon);
  if (lane == 0) {
    atomicAdd(acc, (double)cost);
    atomicAdd(acc + 1, (double)mon);
  }
}

// ---------------- persistent RBM2 CD-5 chain (512<->512), same scratch fix ----------
__global__ __launch_bounds__(256)
void rbm2_chain(const ushort_t* __restrict__ h1in, const ushort_t* __restrict__ W2T,
                const ushort_t* __restrict__ W2N, const ushort_t* __restrict__ bias,
                double* __restrict__ acc, KeyTab kt) {
  __shared__ ushort_t ab[32 * 520];
  __shared__ ushort_t bb[32 * 520];
  const int tid = threadIdx.x, lane = tid & 63, w = tid >> 6;
  const int q = lane >> 4, l16 = lane & 15;
  const int m0 = blockIdx.x * 32;

#pragma unroll
  for (int i = 0; i < 8; i++) {
    int c = i * 256 + tid;
    int r = c >> 6, c8 = (c & 63) * 8;
    *(u16x8*)&ab[r * 520 + c8] = ldnt8(&h1in[(size_t)(m0 + r) * 512 + c8]);
  }
  __syncthreads();

  float cost = 0.f;
  {  // -h1 . bh1t
    float s = 0.f;
    for (int i = tid; i < 32 * 512; i += 256) {
      int r = i >> 9, c = i & 511;
      s += b2f(ab[r * 520 + c]) * b2f(bias[(size_t)(m0 + r) * 1280 + 256 + c]);
    }
    cost -= s;
  }

#pragma unroll 1
  for (int it = 0; it <= 5; it++) {
    // ---- h2-GEMM: z = ab @ W2T^T + bh2t (N=512, K=512) ----
    {
      bf16x8 af[2][2][8];
#pragma unroll
      for (int hf = 0; hf < 2; hf++)
#pragma unroll
        for (int mt = 0; mt < 2; mt++)
#pragma unroll
          for (int ks = 0; ks < 8; ks++)
            af[hf][mt][ks] = *(const bf16x8*)&ab[(mt * 16 + l16) * 520 + hf * 256 +
                                                 ks * 32 + q * 8];
#pragma unroll 1
      for (int nt = 0; nt < 8; nt++) {
        const int n = w * 128 + nt * 16;
        f32x4 ac0 = {0.f, 0.f, 0.f, 0.f}, ac1 = {0.f, 0.f, 0.f, 0.f};
#pragma unroll
        for (int hf = 0; hf < 2; hf++)
#pragma unroll
          for (int ks = 0; ks < 8; ks++) {
            bf16x8 bf = *(const bf16x8*)&W2T[(size_t)(n + l16) * 512 + hf * 256 +
                                             ks * 32 + q * 8];
            ac0 = MFMA16(af[hf][0][ks], bf, ac0);
            ac1 = MFMA16(af[hf][1][ks], bf, ac1);
          }
#pragma unroll
        for (int mt = 0; mt < 2; mt++)
#pragma unroll
          for (int rg = 0; rg < 4; rg++) {
            const int row = mt * 16 + q * 4 + rg, col = n + l16, gr = m0 + row;
            float z = (mt ? ac1[rg] : ac0[rg]) +
                      b2f(bias[(size_t)gr * 1280 + 768 + col]);
            if (it == 0) cost -= softplusf(z);
            if (it == 5) {
              cost += softplusf(z);
            } else {
              float e = __expf(-z);
              float u = fast_uniform(kt.a[10 + 2 * it], kt.b[10 + 2 * it],
                                     (uint32_t)(gr * 512 + col));
              bb[row * 520 + col] = (fmaf(u, e, u) < 1.f) ? (ushort_t)0x3f80
                                                          : (ushort_t)0;
            }
          }
      }
    }
    if (it == 5) break;
    __syncthreads();

    // ---- h1'-GEMM: z = bb @ W2N^T + bh1t (N=512, K=512) ----
    {
      bf16x8 af[2][2][8];
#pragma unroll
      for (int hf = 0; hf < 2; hf++)
#pragma unroll
        for (int mt = 0; mt < 2; mt++)
#pragma unroll
          for (int ks = 0; ks < 8; ks++)
            af[hf][mt][ks] = *(const bf16x8*)&bb[(mt * 16 + l16) * 520 + hf * 256 +
                                                 ks * 32 + q * 8];
#pragma unroll 1
      for (int nt = 0; nt < 8; nt++) {
        const int n = w * 128 + nt * 16;
        f32x4 ac0 = {0.f, 0.f, 0.f, 0.f}, ac1 = {0.f, 0.f, 0.f, 0.f};
#pragma unroll
        for (int hf = 0; hf < 2; hf++)
#pragma unroll
          for (int ks = 0; ks < 8; ks++) {
            bf16x8 bf = *(const bf16x8*)&W2N[(size_t)(n + l16) * 512 + hf * 256 +
                                             ks * 32 + q * 8];
            ac0 = MFMA16(af[hf][0][ks], bf, ac0);
            ac1 = MFMA16(af[hf][1][ks], bf, ac1);
          }
#pragma unroll
        for (int mt = 0; mt < 2; mt++)
#pragma unroll
          for (int rg = 0; rg < 4; rg++) {
            const int row = mt * 16 + q * 4 + rg, col = n + l16, gr = m0 + row;
            float z = (mt ? ac1[rg] : ac0[rg]) +
                      b2f(bias[(size_t)gr * 1280 + 256 + col]);
            float e = __expf(-z);
            float u = fast_uniform(kt.a[11 + 2 * it], kt.b[11 + 2 * it],
                                   (uint32_t)(gr * 512 + col));
            ab[row * 520 + col] = (fmaf(u, e, u) < 1.f) ? (ushort_t)0x3f80
                                                        : (ushort_t)0;
          }
      }
    }
    __syncthreads();
    if (it == 4) {  // +h1fin . bh1t
      float s = 0.f;
      for (int i = tid; i < 32 * 512; i += 256) {
        int r = i >> 9, c = i & 511;
        s += b2f(ab[r * 520 + c]) * b2f(bias[(size_t)(m0 + r) * 1280 + 256 + c]);
      }
      cost += s;
    }
  }
  cost = wave_reduce(cost);
  if (lane == 0) atomicAdd(acc, (double)cost);
}

// ---------------- chunked RNN scan v3 (round-5 proven) ----------------
__global__ __launch_bounds__(512, 2)
void rnn_scan(const float* __restrict__ Apre, const float* __restrict__ Wuu,
              ushort_t* __restrict__ shifted) {
  const int tid = threadIdx.x;
  const int j = tid >> 1;
  const int s = tid & 1;
  const int t_begin = blockIdx.x * 128;
  const int t_end = t_begin + 128;
  const int t0 = (t_begin >= 32) ? (t_begin - 32) : 0;

  float w[128];
#pragma unroll
  for (int i = 0; i < 128; i++) w[i] = Wuu[(size_t)(s * 128 + i) * 256 + j];

  __shared__ float u[2][264];
  __shared__ float asg[16 * 256];
  if (tid < 256) u[0][tid + (tid >> 7) * 4] = 0.f;
  if (blockIdx.x == 0 && s == 0) shifted[j] = 0;
  __syncthreads();

  const int jp = j + (j >> 7) * 4;
  int p = 0;
  for (int tb = t0; tb < t_end; tb += 16) {
    float4 a0 = *(const float4*)&Apre[(size_t)tb * 256 + tid * 8];
    float4 a1 = *(const float4*)&Apre[(size_t)tb * 256 + tid * 8 + 4];
    *(float4*)&asg[tid * 8] = a0;
    *(float4*)&asg[tid * 8 + 4] = a1;
    __syncthreads();
#pragma unroll 1
    for (int i = 0; i < 16; i++) {
      const int t = tb + i;
      float p0 = 0.f, p1 = 0.f, p2 = 0.f, p3 = 0.f;
#pragma unroll
      for (int qq = 0; qq < 128; qq += 4) {
        float4 uv = *(const float4*)&u[p][s * 132 + qq];
        p0 = fmaf(uv.x, w[qq + 0], p0);
        p1 = fmaf(uv.y, w[qq + 1], p1);
        p2 = fmaf(uv.z, w[qq + 2], p2);
        p3 = fmaf(uv.w, w[qq + 3], p3);
      }
      float ps = (p0 + p1) + (p2 + p3);
      ps += __shfl_xor(ps, 1, 64);
      float z = asg[i * 256 + j] + ps;
      float e = __expf(2.f * z);
      float unew = 1.f - 2.f * __builtin_amdgcn_rcpf(e + 1.f);
      if (s == 0) {
        u[1 - p][jp] = unew;
        if (t >= t_begin && (t + 1) < S_LEN)
          shifted[(size_t)(t + 1) * 256 + j] = f2b(unew);
      }
      __syncthreads();
      p ^= 1;
    }
  }
}

// ---------------- prep ----------------
__global__ __launch_bounds__(256)
void conv_b16(const float* __restrict__ src, ushort_t* __restrict__ dst, int n) {
  int i = blockIdx.x * 256 + threadIdx.x;
  if (i < n) dst[i] = f2b(src[i]);
}
__global__ __launch_bounds__(256)
void transp_b16(const float* __restrict__ src, ushort_t* __restrict__ dst, int R, int C) {
  int i = blockIdx.x * 256 + threadIdx.x;
  if (i < R * C) {
    int r = i / C, c = i - r * C;
    dst[(size_t)c * R + r] = f2b(src[i]);
  }
}

__global__ void finalize_kernel(const double* __restrict__ acc, float* __restrict__ out) {
  out[0] = (float)(acc[0] / (double)S_LEN);
  out[1] = (float)(acc[1] / (double)S_LEN);
}

// ---------------- host orchestration ----------------
extern "C" void kernel_launch(void* const* d_in, const int* in_sizes, int n_in,
                              void* d_out, int out_size, void* d_ws, size_t ws_size,
                              hipStream_t stream) {
  (void)in_sizes; (void)n_in; (void)out_size; (void)ws_size;
  const float* v_seq = (const float*)d_in[0];
  const float* W1    = (const float*)d_in[1];
  const float* bv    = (const float*)d_in[2];
  const float* bh1   = (const float*)d_in[3];
  const float* W2    = (const float*)d_in[4];
  const float* bh2   = (const float*)d_in[5];
  const float* Wyv   = (const float*)d_in[6];
  const float* Wyh1  = (const float*)d_in[7];
  const float* Wyh2  = (const float*)d_in[8];
  const float* Wvu   = (const float*)d_in[9];
  const float* Wuu   = (const float*)d_in[10];
  const float* bu    = (const float*)d_in[11];
  float* out = (float*)d_out;

  const size_t SN = (size_t)S_LEN * NV;
  const int NB = NV + NH + NH;  // 1280
  char* base = (char*)d_ws;
  size_t cur = 0;
  auto take = [&](size_t bytes) { size_t o = cur; cur += (bytes + 255) & ~(size_t)255; return o; };
  double*   acc      = (double*)  (base + take(64));
  ushort_t* BTwvu    = (ushort_t*)(base + take(65536 * 2));
  ushort_t* Wycat    = (ushort_t*)(base + take((size_t)NB * NR * 2));
  float*    bveccat  = (float*)   (base + take(NB * 4));
  ushort_t* BTw1     = (ushort_t*)(base + take(131072 * 2));   // W1^T [512,256]
  ushort_t* BTw1t    = (ushort_t*)(base + take(131072 * 2));   // W1   [256,512]
  ushort_t* BTw2     = (ushort_t*)(base + take(262144 * 2));   // W2^T [512,512]
  ushort_t* BTw2t    = (ushort_t*)(base + take(262144 * 2));   // W2   [512,512]
  ushort_t* vseq_bf  = (ushort_t*)(base + take(SN * 2));
  ushort_t* shifted  = (ushort_t*)(base + take(SN * 2));
  ushort_t* bias_cat = (ushort_t*)(base + take((size_t)S_LEN * NB * 2)); // [S,1280]
  ushort_t* h1buf    = (ushort_t*)(base + take((size_t)S_LEN * NH * 2));
  float* Arnn = (float*)bias_cat;  // f32 [S,256] alias; consumed before bias GEMM

  KeyTab kt;
  uint32_t K0 = 0u, K1 = 42u;
  for (int it = 0; it < 10; it++) {
    uint32_t n0, n1, a0, a1, b0, b1;
    tf2x32(K0, K1, 0u, 0u, &n0, &n1);
    tf2x32(K0, K1, 0u, 1u, &a0, &a1);
    tf2x32(K0, K1, 0u, 2u, &b0, &b1);
    kt.a[2 * it] = a0; kt.b[2 * it] = a1;
    kt.a[2 * it + 1] = b0; kt.b[2 * it + 1] = b1;
    K0 = n0; K1 = n1;
  }

  hipMemsetAsync(acc, 0, 2 * sizeof(double), stream);

  dim3 blk(256);
  conv_b16<<<dim3((int)((SN + 255) / 256)), blk, 0, stream>>>(v_seq, vseq_bf, (int)SN);
  conv_b16<<<dim3(256), blk, 0, stream>>>(Wyv, Wycat, 65536);
  conv_b16<<<dim3(512), blk, 0, stream>>>(Wyh1, Wycat + 65536, 131072);
  conv_b16<<<dim3(512), blk, 0, stream>>>(Wyh2, Wycat + 196608, 131072);
  conv_b16<<<dim3(512), blk, 0, stream>>>(W1, BTw1t, 131072);
  conv_b16<<<dim3(1024), blk, 0, stream>>>(W2, BTw2t, 262144);
  transp_b16<<<dim3(256), blk, 0, stream>>>(Wvu, BTwvu, 256, 256);
  transp_b16<<<dim3(512), blk, 0, stream>>>(W1, BTw1, 256, 512);
  transp_b16<<<dim3(1024), blk, 0, stream>>>(W2, BTw2, 512, 512);
  hipMemcpyAsync(bveccat,           bv,  NV * 4, hipMemcpyDeviceToDevice, stream);
  hipMemcpyAsync(bveccat + NV,      bh1, NH * 4, hipMemcpyDeviceToDevice, stream);
  hipMemcpyAsync(bveccat + NV + NH, bh2, NH * 4, hipMemcpyDeviceToDevice, stream);

  const int M = S_LEN;
  gemm_bias<true><<<dim3(NV / 128, M / 128), blk, 0, stream>>>(
      vseq_bf, BTwvu, bu, nullptr, Arnn, M, NV, NV);
  rnn_scan<<<dim3(S_LEN / 128), dim3(512), 0, stream>>>(Arnn, Wuu, shifted);
  gemm_bias<false><<<dim3(NB / 128, M / 128), blk, 0, stream>>>(
      shifted, Wycat, bveccat, bias_cat, nullptr, M, NB, NR);
  rbm1_chain<<<dim3(S_LEN / 32), blk, 0, stream>>>(
      vseq_bf, BTw1, BTw1t, bias_cat, h1buf, acc, kt);
  rbm2_chain<<<dim3(S_LEN / 32), blk, 0, stream>>>(
      h1buf, BTw2, BTw2t, bias_cat, acc, kt);

  finalize_kernel<<<1, 1, 0, stream>>>(acc, out);
}